// Round 13
// baseline (418.205 us; speedup 1.0000x reference)
//
#include <hip/hip_runtime.h>
#include <hip/hip_bf16.h>
#include <stdint.h>

typedef __hip_bfloat16 bf16;
typedef __attribute__((ext_vector_type(8))) short bv8;    // 8 x bf16 (mfma A/B frag)
typedef __attribute__((ext_vector_type(4))) float f32x4;  // mfma C/D frag

// Problem constants: B=2, T=1024, S_ENC=1024, D=2048, NQ=16, NKV=8, H=256, SKV=2048

__device__ __forceinline__ f32x4 mfma16(bv8 a, bv8 b, f32x4 c) {
  return __builtin_amdgcn_mfma_f32_16x16x32_bf16(a, b, c, 0, 0, 0);
}

__device__ __forceinline__ void gload16(const void* g, void* lds) {
  __builtin_amdgcn_global_load_lds((const __attribute__((address_space(1))) void*)g,
                                   (__attribute__((address_space(3))) void*)lds, 16, 0, 0);
}

__device__ __forceinline__ void storeC(float* p, float v) { *p = v; }
__device__ __forceinline__ void storeC(bf16* p, float v) { *p = __float2bfloat16(v); }

// ---------------- merged elementwise f32 -> bf16 (both activations, 1 launch) ----------------
__global__ void cast2_f32_bf16(const float* __restrict__ a, const float* __restrict__ b,
                               bf16* __restrict__ da, bf16* __restrict__ db, int n4each) {
  int i = blockIdx.x * blockDim.x + threadIdx.x;
  const float* s;
  bf16* d;
  if (i < n4each) { s = a; d = da; }
  else            { s = b; d = db; i -= n4each; }
  float4 v = reinterpret_cast<const float4*>(s)[i];
  bf16 t[4] = {__float2bfloat16(v.x), __float2bfloat16(v.y),
               __float2bfloat16(v.z), __float2bfloat16(v.w)};
  reinterpret_cast<uint64_t*>(d)[i] = *reinterpret_cast<uint64_t*>(t);
}

// ------- ALL weight transposes in one launch: QKV slices + O weight -------
__global__ void transpose_all(const float* __restrict__ q_w, const float* __restrict__ k_w,
                              const float* __restrict__ v_w, const float* __restrict__ o_w,
                              bf16* __restrict__ wqkvt, bf16* __restrict__ owt) {
  __shared__ float tile[32][33];
  const int bid = blockIdx.x;
  const float* s;
  bf16* d;
  int R, C, c0, r0;
  if (bid < 16384) {
    const int z = bid >> 9;
    const int rem = bid & 511;
    s = (z < 16) ? q_w + (size_t)z * 524288
      : (z < 24) ? k_w + (size_t)(z - 16) * 524288
                 : v_w + (size_t)(z - 24) * 524288;
    d = wqkvt + (size_t)z * 524288;
    R = 2048; C = 256;
    c0 = (rem & 7) * 32; r0 = (rem >> 3) * 32;
  } else {
    const int rem = bid - 16384;
    s = o_w; d = owt;
    R = 4096; C = 2048;
    c0 = (rem & 63) * 32; r0 = (rem >> 6) * 32;
  }
  const int x = threadIdx.x, y = threadIdx.y;
#pragma unroll
  for (int i = 0; i < 32; i += 8)
    tile[y + i][x] = s[(size_t)(r0 + y + i) * C + c0 + x];
  __syncthreads();
#pragma unroll
  for (int i = 0; i < 32; i += 8)
    d[(size_t)(c0 + y + i) * R + r0 + x] = __float2bfloat16(tile[x][y + i]);
}

// ------- merged V transpose: z<16 self (ld 8192, t0=0), else cross (ld 4096, t0=1024) -------
__global__ void transpose_v2(const bf16* __restrict__ vself, const bf16* __restrict__ vcross,
                             bf16* __restrict__ dst) {
  __shared__ bf16 tile[32][33];
  const int z = blockIdx.z;
  const int zz = z & 15, b = zz >> 3, kvh = zz & 7;
  const bool cross = z >= 16;
  const bf16* srcb = cross ? vcross : vself;
  const int src_ld = cross ? 4096 : 8192;
  const int t0 = cross ? 1024 : 0;
  const bf16* s = srcb + (size_t)(b * 1024) * src_ld + kvh * 256;
  bf16* d = dst + (size_t)(zz * 256) * 2048 + t0;
  const int h0 = blockIdx.x * 32, tt0 = blockIdx.y * 32;
  const int x = threadIdx.x, y = threadIdx.y;
#pragma unroll
  for (int i = 0; i < 32; i += 8)
    tile[y + i][x] = s[(size_t)(tt0 + y + i) * src_ld + h0 + x];
  __syncthreads();
#pragma unroll
  for (int i = 0; i < 32; i += 8)
    d[(size_t)(h0 + y + i) * 2048 + tt0 + x] = tile[x][y + i];
}

// ---------------- GEMM body (m97 128x128, BK=32) -- kept for O-projection ----------------
template <typename CT>
__device__ __forceinline__ void gemm_body(const bf16* __restrict__ A, const bf16* __restrict__ Bt,
                                          CT* __restrict__ C, int N, int K,
                                          int m0, int n0, int kbase, int ksteps) {
  __shared__ __align__(16) bf16 As[128 * 32];
  __shared__ __align__(16) bf16 Bs[128 * 32];
  const int tid = threadIdx.x;
  const int w = tid >> 6, l = tid & 63;
  const int wr = w >> 1, wc = w & 1;
  const int l15 = l & 15, lhi = l >> 4;
  const bf16* ag = A + (size_t)(m0 + (tid >> 2)) * K + kbase + (tid & 3) * 8;
  const bf16* bg = Bt + (size_t)(n0 + (tid >> 2)) * K + kbase + (tid & 3) * 8;
  bf16* asw = As + w * 512;
  bf16* bsw = Bs + w * 512;
  f32x4 acc[4][4] = {};
  for (int k0 = 0; k0 < ksteps; k0 += 32) {
    gload16(ag + k0, asw);
    gload16(ag + (size_t)64 * K + k0, asw + 2048);
    gload16(bg + k0, bsw);
    gload16(bg + (size_t)64 * K + k0, bsw + 2048);
    asm volatile("s_waitcnt vmcnt(0)" ::: "memory");
    __syncthreads();
    bv8 af[4], bfv[4];
#pragma unroll
    for (int m = 0; m < 4; ++m)
      af[m] = *reinterpret_cast<const bv8*>(As + (wr * 64 + m * 16 + l15) * 32 + lhi * 8);
#pragma unroll
    for (int n = 0; n < 4; ++n)
      bfv[n] = *reinterpret_cast<const bv8*>(Bs + (wc * 64 + n * 16 + l15) * 32 + lhi * 8);
#pragma unroll
    for (int m = 0; m < 4; ++m)
#pragma unroll
      for (int n = 0; n < 4; ++n)
        acc[m][n] = mfma16(af[m], bfv[n], acc[m][n]);
    __syncthreads();
  }
  const int r0 = m0 + wr * 64 + lhi * 4;
  const int c0 = n0 + wc * 64 + l15;
#pragma unroll
  for (int m = 0; m < 4; ++m)
#pragma unroll
    for (int n = 0; n < 4; ++n) {
      f32x4 v = acc[m][n];
#pragma unroll
      for (int j = 0; j < 4; ++j)
        storeC(&C[(size_t)(r0 + m * 16 + j) * N + c0 + n * 16], v[j]);
    }
}

// ---------------- 256x256 pipelined projection GEMM (r10 machinery, fixed swizzle) ----------
// stage one half-tile (128 rows x 64 k-cols, 16KB): 2 gload16/thread; LDS dest linear,
// source pre-swizzled with byte ^= ((row&7)<<4) within the 128B LDS row (rule 21).
__device__ __forceinline__ void stage_half(const bf16* __restrict__ G, int ldg, int row0,
                                           int kcol0, bf16* lds, int tid) {
#pragma unroll
  for (int j = 0; j < 2; ++j) {
    const int idx = tid + j * 512;
    const int r = idx >> 3;
    const int cb = ((idx & 7) * 16) ^ ((r & 7) << 4);  // pre-swizzled source byte col
    gload16(G + (size_t)(row0 + r) * ldg + kcol0 + (cb >> 1), lds + idx * 8);
  }
}

// swizzled fragment read: row-major [128][64] bf16 half-tile, row stride 128B
__device__ __forceinline__ bv8 frag(const bf16* p, int row, int ks, int lhi, int xw) {
  return *reinterpret_cast<const bv8*>(p + row * 64 + (((ks * 64 + lhi * 16) ^ xw) >> 1));
}

// merged self+cross projection, 256^2 tiles, 384 blocks, 512 thr.
// XCD-N-affinity swizzle: xcd=lin&7 owns a fixed B column slice (self: 4 N-tiles = 4MB,
// cross: 2 N-tiles = 2MB -> L2-resident per XCD); consecutive idx share the M-row (A reuse).
// Waves 2M x 4N; per wave 128x64 output (acc[8][4]); BK=64, 4 phases/K-tile, 16 MFMA/phase.
// Staging per tile t (buf d=t&1): p0: A(t+1)->buf d^1; p1: B0(t+2)->buf d; p2: B1(t+2)->buf d.
// vmcnt(8) gate once per tile at p0 (guarantees A(t),B(t) landed; leaves A(t+1)+B(t+1) in
// flight). Raw s_barrier (no compiler vmcnt(0) drain).
__launch_bounds__(512, 2)
__global__ void gemm_proj256(const bf16* __restrict__ hid, const bf16* __restrict__ enc,
                             const bf16* __restrict__ wqkvt, bf16* __restrict__ cself,
                             bf16* __restrict__ ccross) {
  __shared__ __align__(16) bf16 Al[2][2][128 * 64];  // [buf][half] 64KB
  __shared__ __align__(16) bf16 Bl[2][2][128 * 64];  // 64KB
  const int lin = blockIdx.x;
  const int xcd = lin & 7, idx = lin >> 3;  // idx 0..47
  const bf16* A;
  const bf16* Bt;
  bf16* C;
  int N, M0, N0;
  if (idx < 32) {  // self: 8 M x 32 N tiles; xcd owns N-tiles 4*xcd..4*xcd+3
    A = hid; Bt = wqkvt; C = cself; N = 8192;
    M0 = (idx >> 2) * 256; N0 = (xcd * 4 + (idx & 3)) * 256;
  } else {         // cross: 8 M x 16 N tiles; xcd owns N-tiles 2*xcd..2*xcd+1
    const int u = idx - 32;
    A = enc; Bt = wqkvt + 8388608; C = ccross; N = 4096;
    M0 = (u >> 1) * 256; N0 = (xcd * 2 + (u & 1)) * 256;
  }
  const int K = 2048, T = 32;  // K-tiles of 64
  const int tid = threadIdx.x, w = tid >> 6, l = tid & 63;
  const int wm = w >> 2, wn = w & 3;
  const int l15 = l & 15, lhi = l >> 4;
  const int xw = (l15 & 7) << 4;

  f32x4 acc[8][4] = {};

  // prologue: A(0)->buf0, B(0)->buf0, B(1)->buf1  (12 loads/thread outstanding)
  stage_half(A, K, M0, 0, Al[0][0], tid);
  stage_half(A, K, M0 + 128, 0, Al[0][1], tid);
  stage_half(Bt, K, N0, 0, Bl[0][0], tid);
  stage_half(Bt, K, N0 + 128, 0, Bl[0][1], tid);
  stage_half(Bt, K, N0, 64, Bl[1][0], tid);
  stage_half(Bt, K, N0 + 128, 64, Bl[1][1], tid);

  for (int t = 0; t < T; ++t) {
    const int d = t & 1;
    const bf16* Ab = Al[d][wm];
    const bf16* Bb = Bl[d][wn >> 1];
    const int rb0 = (wn & 1) * 64;
    const int k1 = (((t + 1) < T) ? (t + 1) : 0) * 64;  // wrap: dummy loads keep vmcnt aligned
    const int k2 = (((t + 2) < T) ? (t + 2) : 0) * 64;
    // ---- phase 0: stage A(t+1); gate; read B(all)+A(q0); 16 MFMA ----
    stage_half(A, K, M0, k1, Al[d ^ 1][0], tid);
    stage_half(A, K, M0 + 128, k1, Al[d ^ 1][1], tid);
    asm volatile("s_waitcnt vmcnt(8)" ::: "memory");  // tile t's 8 loads landed (all waves gate)
    asm volatile("s_barrier" ::: "memory");           // raw: no compiler vmcnt(0) drain
    bv8 bfr[4][2];
#pragma unroll
    for (int i = 0; i < 4; ++i)
#pragma unroll
      for (int ks = 0; ks < 2; ++ks)
        bfr[i][ks] = frag(Bb, rb0 + i * 16 + l15, ks, lhi, xw);
    {
      bv8 af[2][2];
#pragma unroll
      for (int mm = 0; mm < 2; ++mm)
#pragma unroll
        for (int ks = 0; ks < 2; ++ks) af[mm][ks] = frag(Ab, mm * 16 + l15, ks, lhi, xw);
      __builtin_amdgcn_s_setprio(1);
#pragma unroll
      for (int ks = 0; ks < 2; ++ks)
#pragma unroll
        for (int mm = 0; mm < 2; ++mm)
#pragma unroll
          for (int i = 0; i < 4; ++i)
            acc[mm][i] = mfma16(af[mm][ks], bfr[i][ks], acc[mm][i]);
      __builtin_amdgcn_s_setprio(0);
    }
    asm volatile("s_barrier" ::: "memory");
    // ---- phases 1..3: A quad q; stage B(t+2) halves at q=1,2 ----
#pragma unroll
    for (int q = 1; q < 4; ++q) {
      bv8 af[2][2];
#pragma unroll
      for (int mm = 0; mm < 2; ++mm)
#pragma unroll
        for (int ks = 0; ks < 2; ++ks)
          af[mm][ks] = frag(Ab, (q * 2 + mm) * 16 + l15, ks, lhi, xw);
      if (q == 1) stage_half(Bt, K, N0, k2, Bl[d][0], tid);
      if (q == 2) stage_half(Bt, K, N0 + 128, k2, Bl[d][1], tid);
      __builtin_amdgcn_s_setprio(1);
#pragma unroll
      for (int ks = 0; ks < 2; ++ks)
#pragma unroll
        for (int mm = 0; mm < 2; ++mm)
#pragma unroll
          for (int i = 0; i < 4; ++i)
            acc[q * 2 + mm][i] = mfma16(af[mm][ks], bfr[i][ks], acc[q * 2 + mm][i]);
      __builtin_amdgcn_s_setprio(0);
      asm volatile("s_barrier" ::: "memory");
    }
  }
  // epilogue: C write (verified C/D mapping)
  const int r0 = M0 + wm * 128 + lhi * 4;
  const int c0 = N0 + wn * 64 + l15;
#pragma unroll
  for (int m = 0; m < 8; ++m)
#pragma unroll
    for (int i = 0; i < 4; ++i)
#pragma unroll
      for (int j = 0; j < 4; ++j)
        C[(size_t)(r0 + m * 16 + j) * N + c0 + i * 16] = __float2bfloat16(acc[m][i][j]);
}

// O-projection with split-K=4: z=0 -> out, z=1..3 -> partials (all f32 [2048][2048])
__launch_bounds__(256)
__global__ void gemm_osplit(const bf16* __restrict__ A, const bf16* __restrict__ Bt,
                            float* __restrict__ out, float* __restrict__ p1,
                            float* __restrict__ p2, float* __restrict__ p3) {
  const int z = blockIdx.z;
  float* C = (z == 0) ? out : (z == 1) ? p1 : (z == 2) ? p2 : p3;
  gemm_body<float>(A, Bt, C, 2048, 4096, blockIdx.y * 128, blockIdx.x * 128,
                   z * 1024, 1024);
}

// combine: out += p1 + p2 + p3 (float4)
__global__ void add_inplace4(float* __restrict__ out, const float* __restrict__ p1,
                             const float* __restrict__ p2, const float* __restrict__ p3,
                             int n4) {
  int i = blockIdx.x * blockDim.x + threadIdx.x;
  if (i >= n4) return;
  float4 a = reinterpret_cast<float4*>(out)[i];
  float4 b = reinterpret_cast<const float4*>(p1)[i];
  float4 c = reinterpret_cast<const float4*>(p2)[i];
  float4 d = reinterpret_cast<const float4*>(p3)[i];
  a.x += b.x + c.x + d.x;
  a.y += b.y + c.y + d.y;
  a.z += b.z + c.z + d.z;
  a.w += b.w + c.w + d.w;
  reinterpret_cast<float4*>(out)[i] = a;
}

// ---------------- merged RMSNorm (+RoPE) for q / k_self / k_cross in ONE launch ----------------
__launch_bounds__(256)
__global__ void norm_all(const bf16* __restrict__ cself, const bf16* __restrict__ ccross,
                         const float* __restrict__ q_s, const float* __restrict__ k_s,
                         const int* __restrict__ pos_ids,
                         bf16* __restrict__ qb, bf16* __restrict__ kbuf) {
  const int rid = blockIdx.x * 4 + (threadIdx.x >> 6);
  const int l = threadIdx.x & 63;
  const bf16* src;
  const float* scale;
  bf16* dst;
  int r, src_ld, src_col0, nheads, dst_S, dst_t0;
  float mul;
  bool rope;
  if (rid < 32768) {
    r = rid; src = cself; src_ld = 8192; src_col0 = 0; scale = q_s;
    dst = qb; nheads = 16; dst_S = 1024; dst_t0 = 0; mul = 0.0625f; rope = true;
  } else if (rid < 49152) {
    r = rid - 32768; src = cself; src_ld = 8192; src_col0 = 4096; scale = k_s;
    dst = kbuf; nheads = 8; dst_S = 2048; dst_t0 = 0; mul = 1.0f; rope = true;
  } else {
    r = rid - 49152; src = ccross; src_ld = 4096; src_col0 = 0; scale = k_s;
    dst = kbuf; nheads = 8; dst_S = 2048; dst_t0 = 1024; mul = 1.0f; rope = false;
  }
  const int token = r / nheads;  // b*1024 + t
  const int n = r - token * nheads;
  const int b = token >> 10;
  const int t = token & 1023;
  const size_t soff = (size_t)token * src_ld + src_col0 + n * 256 + l * 4;
  bf16 xb[4];
  *reinterpret_cast<uint64_t*>(xb) = *reinterpret_cast<const uint64_t*>(src + soff);
  float x[4];
#pragma unroll
  for (int c = 0; c < 4; ++c) x[c] = __bfloat162float(xb[c]);
  float ss = x[0] * x[0] + x[1] * x[1] + x[2] * x[2] + x[3] * x[3];
#pragma unroll
  for (int d = 1; d < 64; d <<= 1) ss += __shfl_xor(ss, d);
  const float rr = rsqrtf(ss * (1.0f / 256.0f) + 1e-6f);
  float v[4];
#pragma unroll
  for (int c = 0; c < 4; ++c) v[c] = x[c] * rr * (1.0f + scale[l * 4 + c]);
  if (rope) {
    const float pos = (float)pos_ids[token];
    float o[4];
#pragma unroll
    for (int c = 0; c < 4; ++c) {
      const int j = (l & 31) * 4 + c;                              // rotary pair 0..127
      const float inv_ts = exp2f(-(float)j * 0.10381025296523007f);  // 10000^(-j/128)
      const float arg = pos * inv_ts;
      const float sj = sinf(arg), cj = cosf(arg);
      const float partner = __shfl_xor(v[c], 32);
      o[c] = (l < 32) ? (v[c] * cj - partner * sj) : (v[c] * cj + partner * sj);
    }
#pragma unroll
    for (int c = 0; c < 4; ++c) v[c] = o[c];
  }
  bf16 ob[4];
#pragma unroll
  for (int c = 0; c < 4; ++c) ob[c] = __float2bfloat16(v[c] * mul);
  const size_t doff = ((size_t)((b * nheads + n) * dst_S + dst_t0 + t)) * 256 + l * 4;
  *reinterpret_cast<uint64_t*>(dst + doff) = *reinterpret_cast<uint64_t*>(ob);
}

// ---------------- fused attention (r8 machinery + complementary q-pairing, r12) ----------------
__launch_bounds__(512, 2)
__global__ void attn_kernel(const bf16* __restrict__ qb, const bf16* __restrict__ kb,
                            const bf16* __restrict__ vt, bf16* __restrict__ attn_out) {
  __shared__ __align__(16) bf16 Ks[2][64 * 256];   // 32KB each
  __shared__ __align__(16) bf16 Vs[2][256 * 64];   // 32KB each
  __shared__ __align__(16) bf16 pbuf[2][64 * 72];  // [g][4 slots x 16 rows][72 pad]
  __shared__ float rsb[2][4][2][4][4];             // [g][slot][sh][j][lhi]
  const int lin = blockIdx.x + 16 * blockIdx.y;
  const int kvc = (lin & 7) | (((lin >> 7) & 1) << 3);  // XCD-coherent
  const int p   = (lin >> 3) & 15;                       // q-pair index
  const int b = kvc >> 3, kvh = kvc & 7;
  const int tid = threadIdx.x, w = tid >> 6, l = tid & 63;
  const int g = w >> 2, i2 = (w >> 1) & 1, sh = w & 1, hq = w & 3;
  const int n = kvh * 2 + g;
  const int l15 = l & 15, lhi = l >> 4;
  const int xr = (l15 & 7) << 4;  // frag-read byte swizzle

  const int rA = p * 32, rB = (31 - p) * 32;  // row bases of the two q32-tiles
  const int ntSelf = ((31 - p) >> 1) + 1;     // self s-tiles staged (B's causal need)
  const int nASelf = (p >> 1) + 1;            // self s-tiles where A is active
  const int nt = ntSelf + 16;

  const bf16* kbase = kb + (size_t)(b * 8 + kvh) * 2048 * 256;
  const bf16* vbase = vt + (size_t)(b * 8 + kvh) * 256 * 2048;

  const bf16* ksrc[4];
  const bf16* vsrc[4];
#pragma unroll
  for (int i = 0; i < 4; ++i) {
    const int r0 = (w * 4 + i) * 2 + (l >> 5);            // K row 0..63
    const int cbs = ((l & 31) * 16) ^ ((r0 & 7) << 4);    // byte in 512B row
    ksrc[i] = kbase + r0 * 256 + (cbs >> 1);
    const int h0 = (w * 4 + i) * 8 + (l >> 3);            // V row (h) 0..255
    const int cbv = ((l & 7) * 16) ^ ((h0 & 7) << 4);     // byte in 128B row
    vsrc[i] = vbase + (size_t)h0 * 2048 + (cbv >> 1);
  }

  // Q fragments: qf[0] = A slot i2 (rows rA+i2*16), qf[1] = B slot i2+2 (rows rB+i2*16)
  bv8 qf[2][8];
#pragma unroll
  for (int h = 0; h < 2; ++h) {
    const int rbase = (h ? rB : rA) + i2 * 16;
    const bf16* qp = qb + ((size_t)(b * 16 + n) * 1024 + rbase + l15) * 256 + lhi * 8;
#pragma unroll
    for (int f = 0; f < 8; ++f) qf[h][f] = *reinterpret_cast<const bv8*>(qp + f * 32);
  }

  f32x4 oacc[4][4] = {};   // [slot][i]
  float rs[2][4] = {};     // [half: 0=A slot i2, 1=B slot i2+2][j]

#pragma unroll
  for (int i = 0; i < 4; ++i) gload16(ksrc[i], &Ks[0][(w * 4 + i) * 512]);
#pragma unroll
  for (int i = 0; i < 4; ++i) gload16(vsrc[i], &Vs[0][(w * 4 + i) * 512]);
  asm volatile("s_waitcnt vmcnt(0)" ::: "memory");
  __syncthreads();

  for (int it = 0; it < nt; ++it) {
    const int cur = it & 1;
    const int s0 = (it < ntSelf) ? it * 64 : 1024 + (it - ntSelf) * 64;
    const bool selfpart = it < ntSelf;
    const bool aAct = (it < nASelf) || !selfpart;  // block-uniform
    if (it + 1 < nt) {
      const int itn = it + 1;
      const int s1 = (itn < ntSelf) ? itn * 64 : 1024 + (itn - ntSelf) * 64;
#pragma unroll
      for (int i = 0; i < 4; ++i)
        gload16(ksrc[i] + (size_t)s1 * 256, &Ks[cur ^ 1][(w * 4 + i) * 512]);
#pragma unroll
      for (int i = 0; i < 4; ++i)
        gload16(vsrc[i] + s1, &Vs[cur ^ 1][(w * 4 + i) * 512]);
    }
    // ---- QK^T: B always, A when active ----
    f32x4 lacc[2][2] = {};  // [half][ss2]
    __builtin_amdgcn_s_setprio(1);
#pragma unroll
    for (int ss2 = 0; ss2 < 2; ++ss2) {
      const int rbase = ((sh * 2 + ss2) * 16 + l15) * 256;
#pragma unroll
      for (int f = 0; f < 8; ++f) {
        const int off = rbase + (((f * 64 + lhi * 16) ^ xr) >> 1);
        bv8 kf = *reinterpret_cast<const bv8*>(&Ks[cur][off]);
        lacc[1][ss2] = mfma16(qf[1][f], kf, lacc[1][ss2]);
        if (aAct) lacc[0][ss2] = mfma16(qf[0][f], kf, lacc[0][ss2]);
      }
    }
    __builtin_amdgcn_s_setprio(0);
    // ---- softcap + mask + exp -> P tile ----
#pragma unroll
    for (int h = 0; h < 2; ++h) {
      if (h == 0 && !aAct) continue;
      const int slot = h ? (i2 + 2) : i2;
      const int rbase = (h ? rB : rA) + i2 * 16;
#pragma unroll
      for (int ss2 = 0; ss2 < 2; ++ss2)
#pragma unroll
        for (int j = 0; j < 4; ++j) {
          const float raw = lacc[h][ss2][j];
          const float e2 = __expf(raw * 0.04f);  // e^(2*raw/50)
          // exp(50*tanh(raw/50)) = exp(50 - 100/(e2+1))
          const int s_idx = s0 + (sh * 2 + ss2) * 16 + l15;
          const int trow = rbase + lhi * 4 + j;
          const bool ok = !selfpart || (s_idx <= trow);
          const float pv = ok ? __expf(50.f - __fdividef(100.f, e2 + 1.f)) : 0.f;
          rs[h][j] += pv;
          pbuf[g][(slot * 16 + lhi * 4 + j) * 72 + (sh * 2 + ss2) * 16 + l15] =
              __float2bfloat16(pv);
        }
    }
    __syncthreads();  // P visible to g-group PV readers
    // ---- PV: B slots always, A slots when active ----
    __builtin_amdgcn_s_setprio(1);
#pragma unroll
    for (int ks = 0; ks < 2; ++ks) {
      bv8 paB[2], paA[2];
#pragma unroll
      for (int q = 0; q < 2; ++q)
        paB[q] = *reinterpret_cast<const bv8*>(
            &pbuf[g][((2 + q) * 16 + l15) * 72 + ks * 32 + lhi * 8]);
      if (aAct)
#pragma unroll
        for (int q = 0; q < 2; ++q)
          paA[q] = *reinterpret_cast<const bv8*>(
              &pbuf[g][(q * 16 + l15) * 72 + ks * 32 + lhi * 8]);
#pragma unroll
      for (int i = 0; i < 4; ++i) {
        const int off = ((hq * 4 + i) * 16 + l15) * 64 + (((ks * 64 + lhi * 16) ^ xr) >> 1);
        bv8 vf = *reinterpret_cast<const bv8*>(&Vs[cur][off]);
        oacc[2][i] = mfma16(paB[0], vf, oacc[2][i]);
        oacc[3][i] = mfma16(paB[1], vf, oacc[3][i]);
        if (aAct) {
          oacc[0][i] = mfma16(paA[0], vf, oacc[0][i]);
          oacc[1][i] = mfma16(paA[1], vf, oacc[1][i]);
        }
      }
    }
    __builtin_amdgcn_s_setprio(0);
    asm volatile("s_waitcnt vmcnt(0)" ::: "memory");  // staged tile landed
    __syncthreads();  // K/V/pbuf reads done; next iter may overwrite
  }
  // ---- rowsum combine across sh halves, then normalize + store ----
#pragma unroll
  for (int h = 0; h < 2; ++h) {
    const int slot = h ? (i2 + 2) : i2;
#pragma unroll
    for (int j = 0; j < 4; ++j) {
      float s = rs[h][j];
      s += __shfl_xor(s, 1);
      s += __shfl_xor(s, 2);
      s += __shfl_xor(s, 4);
      s += __shfl_xor(s, 8);
      if (l15 == 0) rsb[g][slot][sh][j][lhi] = s;
    }
  }
  __syncthreads();
  const int rowb[4] = {rA, rA + 16, rB, rB + 16};
  bf16* op = attn_out + (size_t)(b * 1024) * 4096 + n * 256 + l15;
#pragma unroll
  for (int slot = 0; slot < 4; ++slot) {
    float invr[4];
#pragma unroll
    for (int j = 0; j < 4; ++j)
      invr[j] = 1.0f / (rsb[g][slot][0][j][lhi] + rsb[g][slot][1][j][lhi]);
#pragma unroll
    for (int i = 0; i < 4; ++i)
#pragma unroll
      for (int j = 0; j < 4; ++j)
        op[(size_t)(rowb[slot] + lhi * 4 + j) * 4096 + (hq * 4 + i) * 16] =
            __float2bfloat16(oacc[slot][i][j] * invr[j]);
  }
}

// ---------------- host launcher ----------------
extern "C" void kernel_launch(void* const* d_in, const int* in_sizes, int n_in,
                              void* d_out, int out_size, void* d_ws, size_t ws_size,
                              hipStream_t stream) {
  (void)in_sizes; (void)n_in; (void)out_size; (void)ws_size;
  const float* hidden = (const float*)d_in[0];
  const float* enc    = (const float*)d_in[1];
  const int*   pos    = (const int*)d_in[2];
  // d_in[3] = merged_attention_mask: deterministic (causal|ones) -> computed analytically
  const float* q_w = (const float*)d_in[4];
  const float* k_w = (const float*)d_in[5];
  const float* v_w = (const float*)d_in[6];
  const float* o_w = (const float*)d_in[7];
  const float* q_s = (const float*)d_in[8];
  const float* k_s = (const float*)d_in[9];
  float* out = (float*)d_out;

  // workspace layout (117,440,512 bytes), write-before-read aliasing (single stream):
  char* base = (char*)d_ws;
  bf16* hid_b  = (bf16*)(base + 0);          // [2048][2048]
  bf16* enc_b  = (bf16*)(base + 8388608);    // [2048][2048]
  bf16* qb     = (bf16*)(base + 0);          // [2][16][1024][256]  (aliases hid/enc after proj)
  float* p2    = (float*)(base + 0);         // [2048][2048] f32    (aliases qb after attn)
  bf16* wqkvt  = (bf16*)(base + 16777216);   // [8192][2048] = qwt|kwt|vwt
  bf16* kbuf   = (bf16*)(base + 16777216);   // [2][8][2048][256]   (aliases qwt after proj)
  float* p3    = (float*)(base + 16777216);  // [2048][2048] f32    (aliases kbuf after attn)
  bf16* vtb    = (bf16*)(base + 33554432);   // [2][8][256][2048]
  bf16* owt    = (bf16*)(base + 50331648);   // [2048][4096]
  bf16* cself  = (bf16*)(base + 67108864);   // [2048][8192] = q|k_self|v_self
  bf16* attn_b = (bf16*)(base + 67108864);   // [2048][4096]        (aliases cself)
  float* p1    = (float*)(base + 83886080);  // [2048][2048] f32
  bf16* ccross = (bf16*)(base + 100663296);  // [2048][4096] = k_cross|v_cross

  dim3 tb32(32, 8);
  cast2_f32_bf16<<<8192, 256, 0, stream>>>(hidden, enc, hid_b, enc_b, 1048576);
  transpose_all<<<24576, tb32, 0, stream>>>(q_w, k_w, v_w, o_w, wqkvt, owt);
  gemm_proj256<<<384, 512, 0, stream>>>(hid_b, enc_b, wqkvt, cself, ccross);
  norm_all<<<16384, 256, 0, stream>>>(cself, ccross, q_s, k_s, pos, qb, kbuf);
  transpose_v2<<<dim3(8, 32, 32), tb32, 0, stream>>>(cself + 6144, ccross + 2048, vtb);
  attn_kernel<<<dim3(16, 16), 512, 0, stream>>>(qb, kbuf, vtb, attn_b);
  gemm_osplit<<<dim3(16, 16, 4), 256, 0, stream>>>(attn_b, owt, out, p1, p2, p3);
  add_inplace4<<<4096, 256, 0, stream>>>(out, p1, p2, p3, 1048576);
}

// Round 14
// 367.528 us; speedup vs baseline: 1.1379x; 1.1379x over previous
//
#include <hip/hip_runtime.h>
#include <hip/hip_bf16.h>
#include <stdint.h>

typedef __hip_bfloat16 bf16;
typedef __attribute__((ext_vector_type(8))) short bv8;    // 8 x bf16 (mfma A/B frag)
typedef __attribute__((ext_vector_type(4))) float f32x4;  // mfma C/D frag

// Problem constants: B=2, T=1024, S_ENC=1024, D=2048, NQ=16, NKV=8, H=256, SKV=2048

__device__ __forceinline__ f32x4 mfma16(bv8 a, bv8 b, f32x4 c) {
  return __builtin_amdgcn_mfma_f32_16x16x32_bf16(a, b, c, 0, 0, 0);
}

__device__ __forceinline__ void gload16(const void* g, void* lds) {
  __builtin_amdgcn_global_load_lds((const __attribute__((address_space(1))) void*)g,
                                   (__attribute__((address_space(3))) void*)lds, 16, 0, 0);
}

__device__ __forceinline__ void storeC(float* p, float v) { *p = v; }
__device__ __forceinline__ void storeC(bf16* p, float v) { *p = __float2bfloat16(v); }

// ---------------- merged elementwise f32 -> bf16 (both activations, 1 launch) ----------------
__global__ void cast2_f32_bf16(const float* __restrict__ a, const float* __restrict__ b,
                               bf16* __restrict__ da, bf16* __restrict__ db, int n4each) {
  int i = blockIdx.x * blockDim.x + threadIdx.x;
  const float* s;
  bf16* d;
  if (i < n4each) { s = a; d = da; }
  else            { s = b; d = db; i -= n4each; }
  float4 v = reinterpret_cast<const float4*>(s)[i];
  bf16 t[4] = {__float2bfloat16(v.x), __float2bfloat16(v.y),
               __float2bfloat16(v.z), __float2bfloat16(v.w)};
  reinterpret_cast<uint64_t*>(d)[i] = *reinterpret_cast<uint64_t*>(t);
}

// ------- ALL weight transposes in one launch: QKV slices + O weight -------
__global__ void transpose_all(const float* __restrict__ q_w, const float* __restrict__ k_w,
                              const float* __restrict__ v_w, const float* __restrict__ o_w,
                              bf16* __restrict__ wqkvt, bf16* __restrict__ owt) {
  __shared__ float tile[32][33];
  const int bid = blockIdx.x;
  const float* s;
  bf16* d;
  int R, C, c0, r0;
  if (bid < 16384) {
    const int z = bid >> 9;
    const int rem = bid & 511;
    s = (z < 16) ? q_w + (size_t)z * 524288
      : (z < 24) ? k_w + (size_t)(z - 16) * 524288
                 : v_w + (size_t)(z - 24) * 524288;
    d = wqkvt + (size_t)z * 524288;
    R = 2048; C = 256;
    c0 = (rem & 7) * 32; r0 = (rem >> 3) * 32;
  } else {
    const int rem = bid - 16384;
    s = o_w; d = owt;
    R = 4096; C = 2048;
    c0 = (rem & 63) * 32; r0 = (rem >> 6) * 32;
  }
  const int x = threadIdx.x, y = threadIdx.y;
#pragma unroll
  for (int i = 0; i < 32; i += 8)
    tile[y + i][x] = s[(size_t)(r0 + y + i) * C + c0 + x];
  __syncthreads();
#pragma unroll
  for (int i = 0; i < 32; i += 8)
    d[(size_t)(c0 + y + i) * R + r0 + x] = __float2bfloat16(tile[x][y + i]);
}

// ------- merged V transpose: z<16 self (ld 8192, t0=0), else cross (ld 4096, t0=1024) -------
__global__ void transpose_v2(const bf16* __restrict__ vself, const bf16* __restrict__ vcross,
                             bf16* __restrict__ dst) {
  __shared__ bf16 tile[32][33];
  const int z = blockIdx.z;
  const int zz = z & 15, b = zz >> 3, kvh = zz & 7;
  const bool cross = z >= 16;
  const bf16* srcb = cross ? vcross : vself;
  const int src_ld = cross ? 4096 : 8192;
  const int t0 = cross ? 1024 : 0;
  const bf16* s = srcb + (size_t)(b * 1024) * src_ld + kvh * 256;
  bf16* d = dst + (size_t)(zz * 256) * 2048 + t0;
  const int h0 = blockIdx.x * 32, tt0 = blockIdx.y * 32;
  const int x = threadIdx.x, y = threadIdx.y;
#pragma unroll
  for (int i = 0; i < 32; i += 8)
    tile[y + i][x] = s[(size_t)(tt0 + y + i) * src_ld + h0 + x];
  __syncthreads();
#pragma unroll
  for (int i = 0; i < 32; i += 8)
    d[(size_t)(h0 + y + i) * 2048 + tt0 + x] = tile[x][y + i];
}

// ---------------- GEMM body: C[M][N] = A[M][K] * Bt[N][K]^T (m97 128x128, BK=32) ----------------
template <typename CT>
__device__ __forceinline__ void gemm_body(const bf16* __restrict__ A, const bf16* __restrict__ Bt,
                                          CT* __restrict__ C, int N, int K,
                                          int m0, int n0, int kbase, int ksteps) {
  __shared__ __align__(16) bf16 As[128 * 32];
  __shared__ __align__(16) bf16 Bs[128 * 32];
  const int tid = threadIdx.x;
  const int w = tid >> 6, l = tid & 63;
  const int wr = w >> 1, wc = w & 1;
  const int l15 = l & 15, lhi = l >> 4;
  const bf16* ag = A + (size_t)(m0 + (tid >> 2)) * K + kbase + (tid & 3) * 8;
  const bf16* bg = Bt + (size_t)(n0 + (tid >> 2)) * K + kbase + (tid & 3) * 8;
  bf16* asw = As + w * 512;
  bf16* bsw = Bs + w * 512;
  f32x4 acc[4][4] = {};
  for (int k0 = 0; k0 < ksteps; k0 += 32) {
    gload16(ag + k0, asw);
    gload16(ag + (size_t)64 * K + k0, asw + 2048);
    gload16(bg + k0, bsw);
    gload16(bg + (size_t)64 * K + k0, bsw + 2048);
    asm volatile("s_waitcnt vmcnt(0)" ::: "memory");
    __syncthreads();
    bv8 af[4], bfv[4];
#pragma unroll
    for (int m = 0; m < 4; ++m)
      af[m] = *reinterpret_cast<const bv8*>(As + (wr * 64 + m * 16 + l15) * 32 + lhi * 8);
#pragma unroll
    for (int n = 0; n < 4; ++n)
      bfv[n] = *reinterpret_cast<const bv8*>(Bs + (wc * 64 + n * 16 + l15) * 32 + lhi * 8);
#pragma unroll
    for (int m = 0; m < 4; ++m)
#pragma unroll
      for (int n = 0; n < 4; ++n)
        acc[m][n] = mfma16(af[m], bfv[n], acc[m][n]);
    __syncthreads();
  }
  const int r0 = m0 + wr * 64 + lhi * 4;
  const int c0 = n0 + wc * 64 + l15;
#pragma unroll
  for (int m = 0; m < 4; ++m)
#pragma unroll
    for (int n = 0; n < 4; ++n) {
      f32x4 v = acc[m][n];
#pragma unroll
      for (int j = 0; j < 4; ++j)
        storeC(&C[(size_t)(r0 + m * 16 + j) * N + c0 + n * 16], v[j]);
    }
}

// merged self+cross projection GEMM: bx<64 -> self (N=8192), else cross (N=4096)
__launch_bounds__(256)
__global__ void gemm_proj(const bf16* __restrict__ hid, const bf16* __restrict__ enc,
                          const bf16* __restrict__ wqkvt, bf16* __restrict__ cself,
                          bf16* __restrict__ ccross) {
  const int bx = blockIdx.x;
  const bool cross = bx >= 64;
  const bf16* A = cross ? enc : hid;
  const bf16* Bt = cross ? wqkvt + 8388608 : wqkvt;
  bf16* C = cross ? ccross : cself;
  const int N = cross ? 4096 : 8192;
  const int n0 = (cross ? bx - 64 : bx) * 128;
  gemm_body<bf16>(A, Bt, C, N, 2048, blockIdx.y * 128, n0, 0, 2048);
}

// O-projection with split-K=4: z=0 -> out, z=1..3 -> partials (all f32 [2048][2048])
__launch_bounds__(256)
__global__ void gemm_osplit(const bf16* __restrict__ A, const bf16* __restrict__ Bt,
                            float* __restrict__ out, float* __restrict__ p1,
                            float* __restrict__ p2, float* __restrict__ p3) {
  const int z = blockIdx.z;
  float* C = (z == 0) ? out : (z == 1) ? p1 : (z == 2) ? p2 : p3;
  gemm_body<float>(A, Bt, C, 2048, 4096, blockIdx.y * 128, blockIdx.x * 128,
                   z * 1024, 1024);
}

// combine: out += p1 + p2 + p3 (float4)
__global__ void add_inplace4(float* __restrict__ out, const float* __restrict__ p1,
                             const float* __restrict__ p2, const float* __restrict__ p3,
                             int n4) {
  int i = blockIdx.x * blockDim.x + threadIdx.x;
  if (i >= n4) return;
  float4 a = reinterpret_cast<float4*>(out)[i];
  float4 b = reinterpret_cast<const float4*>(p1)[i];
  float4 c = reinterpret_cast<const float4*>(p2)[i];
  float4 d = reinterpret_cast<const float4*>(p3)[i];
  a.x += b.x + c.x + d.x;
  a.y += b.y + c.y + d.y;
  a.z += b.z + c.z + d.z;
  a.w += b.w + c.w + d.w;
  reinterpret_cast<float4*>(out)[i] = a;
}

// ---------------- merged RMSNorm (+RoPE) for q / k_self / k_cross in ONE launch ----------------
__launch_bounds__(256)
__global__ void norm_all(const bf16* __restrict__ cself, const bf16* __restrict__ ccross,
                         const float* __restrict__ q_s, const float* __restrict__ k_s,
                         const int* __restrict__ pos_ids,
                         bf16* __restrict__ qb, bf16* __restrict__ kbuf) {
  const int rid = blockIdx.x * 4 + (threadIdx.x >> 6);
  const int l = threadIdx.x & 63;
  const bf16* src;
  const float* scale;
  bf16* dst;
  int r, src_ld, src_col0, nheads, dst_S, dst_t0;
  float mul;
  bool rope;
  if (rid < 32768) {
    r = rid; src = cself; src_ld = 8192; src_col0 = 0; scale = q_s;
    dst = qb; nheads = 16; dst_S = 1024; dst_t0 = 0; mul = 0.0625f; rope = true;
  } else if (rid < 49152) {
    r = rid - 32768; src = cself; src_ld = 8192; src_col0 = 4096; scale = k_s;
    dst = kbuf; nheads = 8; dst_S = 2048; dst_t0 = 0; mul = 1.0f; rope = true;
  } else {
    r = rid - 49152; src = ccross; src_ld = 4096; src_col0 = 0; scale = k_s;
    dst = kbuf; nheads = 8; dst_S = 2048; dst_t0 = 1024; mul = 1.0f; rope = false;
  }
  const int token = r / nheads;  // b*1024 + t
  const int n = r - token * nheads;
  const int b = token >> 10;
  const int t = token & 1023;
  const size_t soff = (size_t)token * src_ld + src_col0 + n * 256 + l * 4;
  bf16 xb[4];
  *reinterpret_cast<uint64_t*>(xb) = *reinterpret_cast<const uint64_t*>(src + soff);
  float x[4];
#pragma unroll
  for (int c = 0; c < 4; ++c) x[c] = __bfloat162float(xb[c]);
  float ss = x[0] * x[0] + x[1] * x[1] + x[2] * x[2] + x[3] * x[3];
#pragma unroll
  for (int d = 1; d < 64; d <<= 1) ss += __shfl_xor(ss, d);
  const float rr = rsqrtf(ss * (1.0f / 256.0f) + 1e-6f);
  float v[4];
#pragma unroll
  for (int c = 0; c < 4; ++c) v[c] = x[c] * rr * (1.0f + scale[l * 4 + c]);
  if (rope) {
    const float pos = (float)pos_ids[token];
    float o[4];
#pragma unroll
    for (int c = 0; c < 4; ++c) {
      const int j = (l & 31) * 4 + c;                              // rotary pair 0..127
      const float inv_ts = exp2f(-(float)j * 0.10381025296523007f);  // 10000^(-j/128)
      const float arg = pos * inv_ts;
      const float sj = sinf(arg), cj = cosf(arg);
      const float partner = __shfl_xor(v[c], 32);
      o[c] = (l < 32) ? (v[c] * cj - partner * sj) : (v[c] * cj + partner * sj);
    }
#pragma unroll
    for (int c = 0; c < 4; ++c) v[c] = o[c];
  }
  bf16 ob[4];
#pragma unroll
  for (int c = 0; c < 4; ++c) ob[c] = __float2bfloat16(v[c] * mul);
  const size_t doff = ((size_t)((b * nheads + n) * dst_S + dst_t0 + t)) * 256 + l * 4;
  *reinterpret_cast<uint64_t*>(dst + doff) = *reinterpret_cast<uint64_t*>(ob);
}

// ---------------- fused attention (r8 machinery + complementary q-pairing) ----------------
// 256 blocks (XCD-swizzled: 16 pairs x 16 b*kvh), 512 thr / 8 waves.
// Block (p, kvc) owns q32-tiles qa=p and qb=31-p; slots {0:A0,1:A1,2:B0,3:B1}.
// A-subtiles skipped (wave-uniform) once s exceeds qa's causal range -> per-block
// work ~24.5 full-tile-equivalents for EVERY p (balanced causal load).
__launch_bounds__(512, 2)
__global__ void attn_kernel(const bf16* __restrict__ qb, const bf16* __restrict__ kb,
                            const bf16* __restrict__ vt, bf16* __restrict__ attn_out) {
  __shared__ __align__(16) bf16 Ks[2][64 * 256];   // 32KB each
  __shared__ __align__(16) bf16 Vs[2][256 * 64];   // 32KB each
  __shared__ __align__(16) bf16 pbuf[2][64 * 72];  // [g][4 slots x 16 rows][72 pad]
  __shared__ float rsb[2][4][2][4][4];             // [g][slot][sh][j][lhi]
  const int lin = blockIdx.x + 16 * blockIdx.y;
  const int kvc = (lin & 7) | (((lin >> 7) & 1) << 3);  // XCD-coherent
  const int p   = (lin >> 3) & 15;                       // q-pair index
  const int b = kvc >> 3, kvh = kvc & 7;
  const int tid = threadIdx.x, w = tid >> 6, l = tid & 63;
  const int g = w >> 2, i2 = (w >> 1) & 1, sh = w & 1, hq = w & 3;
  const int n = kvh * 2 + g;
  const int l15 = l & 15, lhi = l >> 4;
  const int xr = (l15 & 7) << 4;  // frag-read byte swizzle

  const int rA = p * 32, rB = (31 - p) * 32;  // row bases of the two q32-tiles
  const int ntSelf = ((31 - p) >> 1) + 1;     // self s-tiles staged (B's causal need)
  const int nASelf = (p >> 1) + 1;            // self s-tiles where A is active
  const int nt = ntSelf + 16;

  const bf16* kbase = kb + (size_t)(b * 8 + kvh) * 2048 * 256;
  const bf16* vbase = vt + (size_t)(b * 8 + kvh) * 256 * 2048;

  const bf16* ksrc[4];
  const bf16* vsrc[4];
#pragma unroll
  for (int i = 0; i < 4; ++i) {
    const int r0 = (w * 4 + i) * 2 + (l >> 5);            // K row 0..63
    const int cbs = ((l & 31) * 16) ^ ((r0 & 7) << 4);    // byte in 512B row
    ksrc[i] = kbase + r0 * 256 + (cbs >> 1);
    const int h0 = (w * 4 + i) * 8 + (l >> 3);            // V row (h) 0..255
    const int cbv = ((l & 7) * 16) ^ ((h0 & 7) << 4);     // byte in 128B row
    vsrc[i] = vbase + (size_t)h0 * 2048 + (cbv >> 1);
  }

  // Q fragments: qf[0] = A slot i2 (rows rA+i2*16), qf[1] = B slot i2+2 (rows rB+i2*16)
  bv8 qf[2][8];
#pragma unroll
  for (int h = 0; h < 2; ++h) {
    const int rbase = (h ? rB : rA) + i2 * 16;
    const bf16* qp = qb + ((size_t)(b * 16 + n) * 1024 + rbase + l15) * 256 + lhi * 8;
#pragma unroll
    for (int f = 0; f < 8; ++f) qf[h][f] = *reinterpret_cast<const bv8*>(qp + f * 32);
  }

  f32x4 oacc[4][4] = {};   // [slot][i]
  float rs[2][4] = {};     // [half: 0=A slot i2, 1=B slot i2+2][j]

#pragma unroll
  for (int i = 0; i < 4; ++i) gload16(ksrc[i], &Ks[0][(w * 4 + i) * 512]);
#pragma unroll
  for (int i = 0; i < 4; ++i) gload16(vsrc[i], &Vs[0][(w * 4 + i) * 512]);
  asm volatile("s_waitcnt vmcnt(0)" ::: "memory");
  __syncthreads();

  for (int it = 0; it < nt; ++it) {
    const int cur = it & 1;
    const int s0 = (it < ntSelf) ? it * 64 : 1024 + (it - ntSelf) * 64;
    const bool selfpart = it < ntSelf;
    const bool aAct = (it < nASelf) || !selfpart;  // block-uniform
    if (it + 1 < nt) {
      const int itn = it + 1;
      const int s1 = (itn < ntSelf) ? itn * 64 : 1024 + (itn - ntSelf) * 64;
#pragma unroll
      for (int i = 0; i < 4; ++i)
        gload16(ksrc[i] + (size_t)s1 * 256, &Ks[cur ^ 1][(w * 4 + i) * 512]);
#pragma unroll
      for (int i = 0; i < 4; ++i)
        gload16(vsrc[i] + s1, &Vs[cur ^ 1][(w * 4 + i) * 512]);
    }
    // ---- QK^T: B always, A when active ----
    f32x4 lacc[2][2] = {};  // [half][ss2]
    __builtin_amdgcn_s_setprio(1);
#pragma unroll
    for (int ss2 = 0; ss2 < 2; ++ss2) {
      const int rbase = ((sh * 2 + ss2) * 16 + l15) * 256;
#pragma unroll
      for (int f = 0; f < 8; ++f) {
        const int off = rbase + (((f * 64 + lhi * 16) ^ xr) >> 1);
        bv8 kf = *reinterpret_cast<const bv8*>(&Ks[cur][off]);
        lacc[1][ss2] = mfma16(qf[1][f], kf, lacc[1][ss2]);
        if (aAct) lacc[0][ss2] = mfma16(qf[0][f], kf, lacc[0][ss2]);
      }
    }
    __builtin_amdgcn_s_setprio(0);
    // ---- softcap + mask + exp -> P tile ----
#pragma unroll
    for (int h = 0; h < 2; ++h) {
      if (h == 0 && !aAct) continue;
      const int slot = h ? (i2 + 2) : i2;
      const int rbase = (h ? rB : rA) + i2 * 16;
#pragma unroll
      for (int ss2 = 0; ss2 < 2; ++ss2)
#pragma unroll
        for (int j = 0; j < 4; ++j) {
          const float raw = lacc[h][ss2][j];
          const float e2 = __expf(raw * 0.04f);  // e^(2*raw/50)
          // exp(50*tanh(raw/50)) = exp(50 - 100/(e2+1))
          const int s_idx = s0 + (sh * 2 + ss2) * 16 + l15;
          const int trow = rbase + lhi * 4 + j;
          const bool ok = !selfpart || (s_idx <= trow);
          const float pv = ok ? __expf(50.f - __fdividef(100.f, e2 + 1.f)) : 0.f;
          rs[h][j] += pv;
          pbuf[g][(slot * 16 + lhi * 4 + j) * 72 + (sh * 2 + ss2) * 16 + l15] =
              __float2bfloat16(pv);
        }
    }
    __syncthreads();  // P visible to g-group PV readers
    // ---- PV: B slots always, A slots when active ----
    __builtin_amdgcn_s_setprio(1);
#pragma unroll
    for (int ks = 0; ks < 2; ++ks) {
      bv8 paB[2], paA[2];
#pragma unroll
      for (int q = 0; q < 2; ++q)
        paB[q] = *reinterpret_cast<const bv8*>(
            &pbuf[g][((2 + q) * 16 + l15) * 72 + ks * 32 + lhi * 8]);
      if (aAct)
#pragma unroll
        for (int q = 0; q < 2; ++q)
          paA[q] = *reinterpret_cast<const bv8*>(
              &pbuf[g][(q * 16 + l15) * 72 + ks * 32 + lhi * 8]);
#pragma unroll
      for (int i = 0; i < 4; ++i) {
        const int off = ((hq * 4 + i) * 16 + l15) * 64 + (((ks * 64 + lhi * 16) ^ xr) >> 1);
        bv8 vf = *reinterpret_cast<const bv8*>(&Vs[cur][off]);
        oacc[2][i] = mfma16(paB[0], vf, oacc[2][i]);
        oacc[3][i] = mfma16(paB[1], vf, oacc[3][i]);
        if (aAct) {
          oacc[0][i] = mfma16(paA[0], vf, oacc[0][i]);
          oacc[1][i] = mfma16(paA[1], vf, oacc[1][i]);
        }
      }
    }
    __builtin_amdgcn_s_setprio(0);
    asm volatile("s_waitcnt vmcnt(0)" ::: "memory");  // staged tile landed
    __syncthreads();  // K/V/pbuf reads done; next iter may overwrite
  }
  // ---- rowsum combine across sh halves, then normalize + store ----
#pragma unroll
  for (int h = 0; h < 2; ++h) {
    const int slot = h ? (i2 + 2) : i2;
#pragma unroll
    for (int j = 0; j < 4; ++j) {
      float s = rs[h][j];
      s += __shfl_xor(s, 1);
      s += __shfl_xor(s, 2);
      s += __shfl_xor(s, 4);
      s += __shfl_xor(s, 8);
      if (l15 == 0) rsb[g][slot][sh][j][lhi] = s;
    }
  }
  __syncthreads();
  const int rowb[4] = {rA, rA + 16, rB, rB + 16};
  bf16* op = attn_out + (size_t)(b * 1024) * 4096 + n * 256 + l15;
#pragma unroll
  for (int slot = 0; slot < 4; ++slot) {
    float invr[4];
#pragma unroll
    for (int j = 0; j < 4; ++j)
      invr[j] = 1.0f / (rsb[g][slot][0][j][lhi] + rsb[g][slot][1][j][lhi]);
#pragma unroll
    for (int i = 0; i < 4; ++i)
#pragma unroll
      for (int j = 0; j < 4; ++j)
        op[(size_t)(rowb[slot] + lhi * 4 + j) * 4096 + (hq * 4 + i) * 16] =
            __float2bfloat16(oacc[slot][i][j] * invr[j]);
  }
}

// ---------------- host launcher ----------------
extern "C" void kernel_launch(void* const* d_in, const int* in_sizes, int n_in,
                              void* d_out, int out_size, void* d_ws, size_t ws_size,
                              hipStream_t stream) {
  (void)in_sizes; (void)n_in; (void)out_size; (void)ws_size;
  const float* hidden = (const float*)d_in[0];
  const float* enc    = (const float*)d_in[1];
  const int*   pos    = (const int*)d_in[2];
  // d_in[3] = merged_attention_mask: deterministic (causal|ones) -> computed analytically
  const float* q_w = (const float*)d_in[4];
  const float* k_w = (const float*)d_in[5];
  const float* v_w = (const float*)d_in[6];
  const float* o_w = (const float*)d_in[7];
  const float* q_s = (const float*)d_in[8];
  const float* k_s = (const float*)d_in[9];
  float* out = (float*)d_out;

  // workspace layout (117,440,512 bytes), write-before-read aliasing (single stream):
  char* base = (char*)d_ws;
  bf16* hid_b  = (bf16*)(base + 0);          // [2048][2048]
  bf16* enc_b  = (bf16*)(base + 8388608);    // [2048][2048]
  bf16* qb     = (bf16*)(base + 0);          // [2][16][1024][256]  (aliases hid/enc after proj)
  float* p2    = (float*)(base + 0);         // [2048][2048] f32    (aliases qb after attn)
  bf16* wqkvt  = (bf16*)(base + 16777216);   // [8192][2048] = qwt|kwt|vwt
  bf16* kbuf   = (bf16*)(base + 16777216);   // [2][8][2048][256]   (aliases qwt after proj)
  float* p3    = (float*)(base + 16777216);  // [2048][2048] f32    (aliases kbuf after attn)
  bf16* vtb    = (bf16*)(base + 33554432);   // [2][8][256][2048]
  bf16* owt    = (bf16*)(base + 50331648);   // [2048][4096]
  bf16* cself  = (bf16*)(base + 67108864);   // [2048][8192] = q|k_self|v_self
  bf16* attn_b = (bf16*)(base + 67108864);   // [2048][4096]        (aliases cself)
  float* p1    = (float*)(base + 83886080);  // [2048][2048] f32
  bf16* ccross = (bf16*)(base + 100663296);  // [2048][4096] = k_cross|v_cross

  dim3 tb32(32, 8);
  cast2_f32_bf16<<<8192, 256, 0, stream>>>(hidden, enc, hid_b, enc_b, 1048576);
  transpose_all<<<24576, tb32, 0, stream>>>(q_w, k_w, v_w, o_w, wqkvt, owt);
  gemm_proj<<<dim3(96, 16), 256, 0, stream>>>(hid_b, enc_b, wqkvt, cself, ccross);
  norm_all<<<16384, 256, 0, stream>>>(cself, ccross, q_s, k_s, pos, qb, kbuf);
  transpose_v2<<<dim3(8, 32, 32), tb32, 0, stream>>>(cself + 6144, ccross + 2048, vtb);
  attn_kernel<<<dim3(16, 16), 512, 0, stream>>>(qb, kbuf, vtb, attn_b);
  gemm_osplit<<<dim3(16, 16, 4), 256, 0, stream>>>(attn_b, owt, out, p1, p2, p3);
  add_inplace4<<<4096, 256, 0, stream>>>(out, p1, p2, p3, 1048576);
}

// Round 16
// 366.612 us; speedup vs baseline: 1.1407x; 1.0025x over previous
//
#include <hip/hip_runtime.h>
#include <hip/hip_bf16.h>
#include <stdint.h>

typedef __hip_bfloat16 bf16;
typedef __attribute__((ext_vector_type(8))) short bv8;    // 8 x bf16 (mfma A/B frag)
typedef __attribute__((ext_vector_type(4))) float f32x4;  // mfma C/D frag

// Problem constants: B=2, T=1024, S_ENC=1024, D=2048, NQ=16, NKV=8, H=256, SKV=2048

__device__ __forceinline__ f32x4 mfma16(bv8 a, bv8 b, f32x4 c) {
  return __builtin_amdgcn_mfma_f32_16x16x32_bf16(a, b, c, 0, 0, 0);
}

__device__ __forceinline__ void gload16(const void* g, void* lds) {
  __builtin_amdgcn_global_load_lds((const __attribute__((address_space(1))) void*)g,
                                   (__attribute__((address_space(3))) void*)lds, 16, 0, 0);
}

__device__ __forceinline__ void storeC(float* p, float v) { *p = v; }
__device__ __forceinline__ void storeC(bf16* p, float v) { *p = __float2bfloat16(v); }

// ---------------- merged elementwise f32 -> bf16 (both activations, 1 launch) ----------------
__global__ void cast2_f32_bf16(const float* __restrict__ a, const float* __restrict__ b,
                               bf16* __restrict__ da, bf16* __restrict__ db, int n4each) {
  int i = blockIdx.x * blockDim.x + threadIdx.x;
  const float* s;
  bf16* d;
  if (i < n4each) { s = a; d = da; }
  else            { s = b; d = db; i -= n4each; }
  float4 v = reinterpret_cast<const float4*>(s)[i];
  bf16 t[4] = {__float2bfloat16(v.x), __float2bfloat16(v.y),
               __float2bfloat16(v.z), __float2bfloat16(v.w)};
  reinterpret_cast<uint64_t*>(d)[i] = *reinterpret_cast<uint64_t*>(t);
}

// ------- ALL weight transposes in one launch: QKV slices + O weight -------
__global__ void transpose_all(const float* __restrict__ q_w, const float* __restrict__ k_w,
                              const float* __restrict__ v_w, const float* __restrict__ o_w,
                              bf16* __restrict__ wqkvt, bf16* __restrict__ owt) {
  __shared__ float tile[32][33];
  const int bid = blockIdx.x;
  const float* s;
  bf16* d;
  int R, C, c0, r0;
  if (bid < 16384) {
    const int z = bid >> 9;
    const int rem = bid & 511;
    s = (z < 16) ? q_w + (size_t)z * 524288
      : (z < 24) ? k_w + (size_t)(z - 16) * 524288
                 : v_w + (size_t)(z - 24) * 524288;
    d = wqkvt + (size_t)z * 524288;
    R = 2048; C = 256;
    c0 = (rem & 7) * 32; r0 = (rem >> 3) * 32;
  } else {
    const int rem = bid - 16384;
    s = o_w; d = owt;
    R = 4096; C = 2048;
    c0 = (rem & 63) * 32; r0 = (rem >> 6) * 32;
  }
  const int x = threadIdx.x, y = threadIdx.y;
#pragma unroll
  for (int i = 0; i < 32; i += 8)
    tile[y + i][x] = s[(size_t)(r0 + y + i) * C + c0 + x];
  __syncthreads();
#pragma unroll
  for (int i = 0; i < 32; i += 8)
    d[(size_t)(c0 + y + i) * R + r0 + x] = __float2bfloat16(tile[x][y + i]);
}

// ------- merged V transpose: z<16 self (ld 8192, t0=0), else cross (ld 4096, t0=1024) -------
__global__ void transpose_v2(const bf16* __restrict__ vself, const bf16* __restrict__ vcross,
                             bf16* __restrict__ dst) {
  __shared__ bf16 tile[32][33];
  const int z = blockIdx.z;
  const int zz = z & 15, b = zz >> 3, kvh = zz & 7;
  const bool cross = z >= 16;
  const bf16* srcb = cross ? vcross : vself;
  const int src_ld = cross ? 4096 : 8192;
  const int t0 = cross ? 1024 : 0;
  const bf16* s = srcb + (size_t)(b * 1024) * src_ld + kvh * 256;
  bf16* d = dst + (size_t)(zz * 256) * 2048 + t0;
  const int h0 = blockIdx.x * 32, tt0 = blockIdx.y * 32;
  const int x = threadIdx.x, y = threadIdx.y;
#pragma unroll
  for (int i = 0; i < 32; i += 8)
    tile[y + i][x] = s[(size_t)(tt0 + y + i) * src_ld + h0 + x];
  __syncthreads();
#pragma unroll
  for (int i = 0; i < 32; i += 8)
    d[(size_t)(h0 + y + i) * 2048 + tt0 + x] = tile[x][y + i];
}

// ---------------- GEMM body: C[M][N] = A[M][K] * Bt[N][K]^T (m97 128x128, BK=32) ----------------
template <typename CT>
__device__ __forceinline__ void gemm_body(const bf16* __restrict__ A, const bf16* __restrict__ Bt,
                                          CT* __restrict__ C, int N, int K,
                                          int m0, int n0, int kbase, int ksteps) {
  __shared__ __align__(16) bf16 As[128 * 32];
  __shared__ __align__(16) bf16 Bs[128 * 32];
  const int tid = threadIdx.x;
  const int w = tid >> 6, l = tid & 63;
  const int wr = w >> 1, wc = w & 1;
  const int l15 = l & 15, lhi = l >> 4;
  const bf16* ag = A + (size_t)(m0 + (tid >> 2)) * K + kbase + (tid & 3) * 8;
  const bf16* bg = Bt + (size_t)(n0 + (tid >> 2)) * K + kbase + (tid & 3) * 8;
  bf16* asw = As + w * 512;
  bf16* bsw = Bs + w * 512;
  f32x4 acc[4][4] = {};
  for (int k0 = 0; k0 < ksteps; k0 += 32) {
    gload16(ag + k0, asw);
    gload16(ag + (size_t)64 * K + k0, asw + 2048);
    gload16(bg + k0, bsw);
    gload16(bg + (size_t)64 * K + k0, bsw + 2048);
    asm volatile("s_waitcnt vmcnt(0)" ::: "memory");
    __syncthreads();
    bv8 af[4], bfv[4];
#pragma unroll
    for (int m = 0; m < 4; ++m)
      af[m] = *reinterpret_cast<const bv8*>(As + (wr * 64 + m * 16 + l15) * 32 + lhi * 8);
#pragma unroll
    for (int n = 0; n < 4; ++n)
      bfv[n] = *reinterpret_cast<const bv8*>(Bs + (wc * 64 + n * 16 + l15) * 32 + lhi * 8);
#pragma unroll
    for (int m = 0; m < 4; ++m)
#pragma unroll
      for (int n = 0; n < 4; ++n)
        acc[m][n] = mfma16(af[m], bfv[n], acc[m][n]);
    __syncthreads();
  }
  const int r0 = m0 + wr * 64 + lhi * 4;
  const int c0 = n0 + wc * 64 + l15;
#pragma unroll
  for (int m = 0; m < 4; ++m)
#pragma unroll
    for (int n = 0; n < 4; ++n) {
      f32x4 v = acc[m][n];
#pragma unroll
      for (int j = 0; j < 4; ++j)
        storeC(&C[(size_t)(r0 + m * 16 + j) * N + c0 + n * 16], v[j]);
    }
}

// merged self+cross projection GEMM: bx<64 -> self (N=8192), else cross (N=4096)
__launch_bounds__(256)
__global__ void gemm_proj(const bf16* __restrict__ hid, const bf16* __restrict__ enc,
                          const bf16* __restrict__ wqkvt, bf16* __restrict__ cself,
                          bf16* __restrict__ ccross) {
  const int bx = blockIdx.x;
  const bool cross = bx >= 64;
  const bf16* A = cross ? enc : hid;
  const bf16* Bt = cross ? wqkvt + 8388608 : wqkvt;
  bf16* C = cross ? ccross : cself;
  const int N = cross ? 4096 : 8192;
  const int n0 = (cross ? bx - 64 : bx) * 128;
  gemm_body<bf16>(A, Bt, C, N, 2048, blockIdx.y * 128, n0, 0, 2048);
}

// O-projection with split-K=4: z=0 -> out, z=1..3 -> partials (all f32 [2048][2048])
__launch_bounds__(256)
__global__ void gemm_osplit(const bf16* __restrict__ A, const bf16* __restrict__ Bt,
                            float* __restrict__ out, float* __restrict__ p1,
                            float* __restrict__ p2, float* __restrict__ p3) {
  const int z = blockIdx.z;
  float* C = (z == 0) ? out : (z == 1) ? p1 : (z == 2) ? p2 : p3;
  gemm_body<float>(A, Bt, C, 2048, 4096, blockIdx.y * 128, blockIdx.x * 128,
                   z * 1024, 1024);
}

// combine: out += p1 + p2 + p3 (float4)
__global__ void add_inplace4(float* __restrict__ out, const float* __restrict__ p1,
                             const float* __restrict__ p2, const float* __restrict__ p3,
                             int n4) {
  int i = blockIdx.x * blockDim.x + threadIdx.x;
  if (i >= n4) return;
  float4 a = reinterpret_cast<float4*>(out)[i];
  float4 b = reinterpret_cast<const float4*>(p1)[i];
  float4 c = reinterpret_cast<const float4*>(p2)[i];
  float4 d = reinterpret_cast<const float4*>(p3)[i];
  a.x += b.x + c.x + d.x;
  a.y += b.y + c.y + d.y;
  a.z += b.z + c.z + d.z;
  a.w += b.w + c.w + d.w;
  reinterpret_cast<float4*>(out)[i] = a;
}

// ---------------- merged RMSNorm (+RoPE) for q / k_self / k_cross in ONE launch ----------------
__launch_bounds__(256)
__global__ void norm_all(const bf16* __restrict__ cself, const bf16* __restrict__ ccross,
                         const float* __restrict__ q_s, const float* __restrict__ k_s,
                         const int* __restrict__ pos_ids,
                         bf16* __restrict__ qb, bf16* __restrict__ kbuf) {
  const int rid = blockIdx.x * 4 + (threadIdx.x >> 6);
  const int l = threadIdx.x & 63;
  const bf16* src;
  const float* scale;
  bf16* dst;
  int r, src_ld, src_col0, nheads, dst_S, dst_t0;
  float mul;
  bool rope;
  if (rid < 32768) {
    r = rid; src = cself; src_ld = 8192; src_col0 = 0; scale = q_s;
    dst = qb; nheads = 16; dst_S = 1024; dst_t0 = 0; mul = 0.0625f; rope = true;
  } else if (rid < 49152) {
    r = rid - 32768; src = cself; src_ld = 8192; src_col0 = 4096; scale = k_s;
    dst = kbuf; nheads = 8; dst_S = 2048; dst_t0 = 0; mul = 1.0f; rope = true;
  } else {
    r = rid - 49152; src = ccross; src_ld = 4096; src_col0 = 0; scale = k_s;
    dst = kbuf; nheads = 8; dst_S = 2048; dst_t0 = 1024; mul = 1.0f; rope = false;
  }
  const int token = r / nheads;  // b*1024 + t
  const int n = r - token * nheads;
  const int b = token >> 10;
  const int t = token & 1023;
  const size_t soff = (size_t)token * src_ld + src_col0 + n * 256 + l * 4;
  bf16 xb[4];
  *reinterpret_cast<uint64_t*>(xb) = *reinterpret_cast<const uint64_t*>(src + soff);
  float x[4];
#pragma unroll
  for (int c = 0; c < 4; ++c) x[c] = __bfloat162float(xb[c]);
  float ss = x[0] * x[0] + x[1] * x[1] + x[2] * x[2] + x[3] * x[3];
#pragma unroll
  for (int d = 1; d < 64; d <<= 1) ss += __shfl_xor(ss, d);
  const float rr = rsqrtf(ss * (1.0f / 256.0f) + 1e-6f);
  float v[4];
#pragma unroll
  for (int c = 0; c < 4; ++c) v[c] = x[c] * rr * (1.0f + scale[l * 4 + c]);
  if (rope) {
    const float pos = (float)pos_ids[token];
    float o[4];
#pragma unroll
    for (int c = 0; c < 4; ++c) {
      const int j = (l & 31) * 4 + c;                              // rotary pair 0..127
      const float inv_ts = exp2f(-(float)j * 0.10381025296523007f);  // 10000^(-j/128)
      const float arg = pos * inv_ts;
      const float sj = sinf(arg), cj = cosf(arg);
      const float partner = __shfl_xor(v[c], 32);
      o[c] = (l < 32) ? (v[c] * cj - partner * sj) : (v[c] * cj + partner * sj);
    }
#pragma unroll
    for (int c = 0; c < 4; ++c) v[c] = o[c];
  }
  bf16 ob[4];
#pragma unroll
  for (int c = 0; c < 4; ++c) ob[c] = __float2bfloat16(v[c] * mul);
  const size_t doff = ((size_t)((b * nheads + n) * dst_S + dst_t0 + t)) * 256 + l * 4;
  *reinterpret_cast<uint64_t*>(dst + doff) = *reinterpret_cast<uint64_t*>(ob);
}

// ---------------- fused attention (r8 machinery + complementary q-pairing) ----------------
// 256 blocks (XCD-swizzled: 16 pairs x 16 b*kvh), 512 thr / 8 waves.
// Block (p, kvc) owns q32-tiles qa=p and qb=31-p; slots {0:A0,1:A1,2:B0,3:B1}.
// A-subtiles skipped (wave-uniform) once s exceeds qa's causal range -> per-block
// work ~24.5 full-tile-equivalents for EVERY p (balanced causal load).
__launch_bounds__(512, 2)
__global__ void attn_kernel(const bf16* __restrict__ qb, const bf16* __restrict__ kb,
                            const bf16* __restrict__ vt, bf16* __restrict__ attn_out) {
  __shared__ __align__(16) bf16 Ks[2][64 * 256];   // 32KB each
  __shared__ __align__(16) bf16 Vs[2][256 * 64];   // 32KB each
  __shared__ __align__(16) bf16 pbuf[2][64 * 72];  // [g][4 slots x 16 rows][72 pad]
  __shared__ float rsb[2][4][2][4][4];             // [g][slot][sh][j][lhi]
  const int lin = blockIdx.x + 16 * blockIdx.y;
  const int kvc = (lin & 7) | (((lin >> 7) & 1) << 3);  // XCD-coherent
  const int p   = (lin >> 3) & 15;                       // q-pair index
  const int b = kvc >> 3, kvh = kvc & 7;
  const int tid = threadIdx.x, w = tid >> 6, l = tid & 63;
  const int g = w >> 2, i2 = (w >> 1) & 1, sh = w & 1, hq = w & 3;
  const int n = kvh * 2 + g;
  const int l15 = l & 15, lhi = l >> 4;
  const int xr = (l15 & 7) << 4;  // frag-read byte swizzle

  const int rA = p * 32, rB = (31 - p) * 32;  // row bases of the two q32-tiles
  const int ntSelf = ((31 - p) >> 1) + 1;     // self s-tiles staged (B's causal need)
  const int nASelf = (p >> 1) + 1;            // self s-tiles where A is active
  const int nt = ntSelf + 16;

  const bf16* kbase = kb + (size_t)(b * 8 + kvh) * 2048 * 256;
  const bf16* vbase = vt + (size_t)(b * 8 + kvh) * 256 * 2048;

  const bf16* ksrc[4];
  const bf16* vsrc[4];
#pragma unroll
  for (int i = 0; i < 4; ++i) {
    const int r0 = (w * 4 + i) * 2 + (l >> 5);            // K row 0..63
    const int cbs = ((l & 31) * 16) ^ ((r0 & 7) << 4);    // byte in 512B row
    ksrc[i] = kbase + r0 * 256 + (cbs >> 1);
    const int h0 = (w * 4 + i) * 8 + (l >> 3);            // V row (h) 0..255
    const int cbv = ((l & 7) * 16) ^ ((h0 & 7) << 4);     // byte in 128B row
    vsrc[i] = vbase + (size_t)h0 * 2048 + (cbv >> 1);
  }

  // Q fragments: qf[0] = A slot i2 (rows rA+i2*16), qf[1] = B slot i2+2 (rows rB+i2*16)
  bv8 qf[2][8];
#pragma unroll
  for (int h = 0; h < 2; ++h) {
    const int rbase = (h ? rB : rA) + i2 * 16;
    const bf16* qp = qb + ((size_t)(b * 16 + n) * 1024 + rbase + l15) * 256 + lhi * 8;
#pragma unroll
    for (int f = 0; f < 8; ++f) qf[h][f] = *reinterpret_cast<const bv8*>(qp + f * 32);
  }

  f32x4 oacc[4][4] = {};   // [slot][i]
  float rs[2][4] = {};     // [half: 0=A slot i2, 1=B slot i2+2][j]

#pragma unroll
  for (int i = 0; i < 4; ++i) gload16(ksrc[i], &Ks[0][(w * 4 + i) * 512]);
#pragma unroll
  for (int i = 0; i < 4; ++i) gload16(vsrc[i], &Vs[0][(w * 4 + i) * 512]);
  asm volatile("s_waitcnt vmcnt(0)" ::: "memory");
  __syncthreads();

  for (int it = 0; it < nt; ++it) {
    const int cur = it & 1;
    const int s0 = (it < ntSelf) ? it * 64 : 1024 + (it - ntSelf) * 64;
    const bool selfpart = it < ntSelf;
    const bool aAct = (it < nASelf) || !selfpart;  // block-uniform
    if (it + 1 < nt) {
      const int itn = it + 1;
      const int s1 = (itn < ntSelf) ? itn * 64 : 1024 + (itn - ntSelf) * 64;
#pragma unroll
      for (int i = 0; i < 4; ++i)
        gload16(ksrc[i] + (size_t)s1 * 256, &Ks[cur ^ 1][(w * 4 + i) * 512]);
#pragma unroll
      for (int i = 0; i < 4; ++i)
        gload16(vsrc[i] + s1, &Vs[cur ^ 1][(w * 4 + i) * 512]);
    }
    // ---- QK^T: B always, A when active ----
    f32x4 lacc[2][2] = {};  // [half][ss2]
    __builtin_amdgcn_s_setprio(1);
#pragma unroll
    for (int ss2 = 0; ss2 < 2; ++ss2) {
      const int rbase = ((sh * 2 + ss2) * 16 + l15) * 256;
#pragma unroll
      for (int f = 0; f < 8; ++f) {
        const int off = rbase + (((f * 64 + lhi * 16) ^ xr) >> 1);
        bv8 kf = *reinterpret_cast<const bv8*>(&Ks[cur][off]);
        lacc[1][ss2] = mfma16(qf[1][f], kf, lacc[1][ss2]);
        if (aAct) lacc[0][ss2] = mfma16(qf[0][f], kf, lacc[0][ss2]);
      }
    }
    __builtin_amdgcn_s_setprio(0);
    // ---- softcap + mask + exp -> P tile ----
#pragma unroll
    for (int h = 0; h < 2; ++h) {
      if (h == 0 && !aAct) continue;
      const int slot = h ? (i2 + 2) : i2;
      const int rbase = (h ? rB : rA) + i2 * 16;
#pragma unroll
      for (int ss2 = 0; ss2 < 2; ++ss2)
#pragma unroll
        for (int j = 0; j < 4; ++j) {
          const float raw = lacc[h][ss2][j];
          const float e2 = __expf(raw * 0.04f);  // e^(2*raw/50)
          // exp(50*tanh(raw/50)) = exp(50 - 100/(e2+1))
          const int s_idx = s0 + (sh * 2 + ss2) * 16 + l15;
          const int trow = rbase + lhi * 4 + j;
          const bool ok = !selfpart || (s_idx <= trow);
          const float pv = ok ? __expf(50.f - __fdividef(100.f, e2 + 1.f)) : 0.f;
          rs[h][j] += pv;
          pbuf[g][(slot * 16 + lhi * 4 + j) * 72 + (sh * 2 + ss2) * 16 + l15] =
              __float2bfloat16(pv);
        }
    }
    __syncthreads();  // P visible to g-group PV readers
    // ---- PV: B slots always, A slots when active ----
    __builtin_amdgcn_s_setprio(1);
#pragma unroll
    for (int ks = 0; ks < 2; ++ks) {
      bv8 paB[2], paA[2];
#pragma unroll
      for (int q = 0; q < 2; ++q)
        paB[q] = *reinterpret_cast<const bv8*>(
            &pbuf[g][((2 + q) * 16 + l15) * 72 + ks * 32 + lhi * 8]);
      if (aAct)
#pragma unroll
        for (int q = 0; q < 2; ++q)
          paA[q] = *reinterpret_cast<const bv8*>(
              &pbuf[g][(q * 16 + l15) * 72 + ks * 32 + lhi * 8]);
#pragma unroll
      for (int i = 0; i < 4; ++i) {
        const int off = ((hq * 4 + i) * 16 + l15) * 64 + (((ks * 64 + lhi * 16) ^ xr) >> 1);
        bv8 vf = *reinterpret_cast<const bv8*>(&Vs[cur][off]);
        oacc[2][i] = mfma16(paB[0], vf, oacc[2][i]);
        oacc[3][i] = mfma16(paB[1], vf, oacc[3][i]);
        if (aAct) {
          oacc[0][i] = mfma16(paA[0], vf, oacc[0][i]);
          oacc[1][i] = mfma16(paA[1], vf, oacc[1][i]);
        }
      }
    }
    __builtin_amdgcn_s_setprio(0);
    asm volatile("s_waitcnt vmcnt(0)" ::: "memory");  // staged tile landed
    __syncthreads();  // K/V/pbuf reads done; next iter may overwrite
  }
  // ---- rowsum combine across sh halves, then normalize + store ----
#pragma unroll
  for (int h = 0; h < 2; ++h) {
    const int slot = h ? (i2 + 2) : i2;
#pragma unroll
    for (int j = 0; j < 4; ++j) {
      float s = rs[h][j];
      s += __shfl_xor(s, 1);
      s += __shfl_xor(s, 2);
      s += __shfl_xor(s, 4);
      s += __shfl_xor(s, 8);
      if (l15 == 0) rsb[g][slot][sh][j][lhi] = s;
    }
  }
  __syncthreads();
  const int rowb[4] = {rA, rA + 16, rB, rB + 16};
  bf16* op = attn_out + (size_t)(b * 1024) * 4096 + n * 256 + l15;
#pragma unroll
  for (int slot = 0; slot < 4; ++slot) {
    float invr[4];
#pragma unroll
    for (int j = 0; j < 4; ++j)
      invr[j] = 1.0f / (rsb[g][slot][0][j][lhi] + rsb[g][slot][1][j][lhi]);
#pragma unroll
    for (int i = 0; i < 4; ++i)
#pragma unroll
      for (int j = 0; j < 4; ++j)
        op[(size_t)(rowb[slot] + lhi * 4 + j) * 4096 + (hq * 4 + i) * 16] =
            __float2bfloat16(oacc[slot][i][j] * invr[j]);
  }
}

// ---------------- host launcher ----------------
extern "C" void kernel_launch(void* const* d_in, const int* in_sizes, int n_in,
                              void* d_out, int out_size, void* d_ws, size_t ws_size,
                              hipStream_t stream) {
  (void)in_sizes; (void)n_in; (void)out_size; (void)ws_size;
  const float* hidden = (const float*)d_in[0];
  const float* enc    = (const float*)d_in[1];
  const int*   pos    = (const int*)d_in[2];
  // d_in[3] = merged_attention_mask: deterministic (causal|ones) -> computed analytically
  const float* q_w = (const float*)d_in[4];
  const float* k_w = (const float*)d_in[5];
  const float* v_w = (const float*)d_in[6];
  const float* o_w = (const float*)d_in[7];
  const float* q_s = (const float*)d_in[8];
  const float* k_s = (const float*)d_in[9];
  float* out = (float*)d_out;

  // workspace layout (117,440,512 bytes), write-before-read aliasing (single stream):
  char* base = (char*)d_ws;
  bf16* hid_b  = (bf16*)(base + 0);          // [2048][2048]
  bf16* enc_b  = (bf16*)(base + 8388608);    // [2048][2048]
  bf16* qb     = (bf16*)(base + 0);          // [2][16][1024][256]  (aliases hid/enc after proj)
  float* p2    = (float*)(base + 0);         // [2048][2048] f32    (aliases qb after attn)
  bf16* wqkvt  = (bf16*)(base + 16777216);   // [8192][2048] = qwt|kwt|vwt
  bf16* kbuf   = (bf16*)(base + 16777216);   // [2][8][2048][256]   (aliases qwt after proj)
  float* p3    = (float*)(base + 16777216);  // [2048][2048] f32    (aliases kbuf after attn)
  bf16* vtb    = (bf16*)(base + 33554432);   // [2][8][256][2048]
  bf16* owt    = (bf16*)(base + 50331648);   // [2048][4096]
  bf16* cself  = (bf16*)(base + 67108864);   // [2048][8192] = q|k_self|v_self
  bf16* attn_b = (bf16*)(base + 67108864);   // [2048][4096]        (aliases cself)
  float* p1    = (float*)(base + 83886080);  // [2048][2048] f32
  bf16* ccross = (bf16*)(base + 100663296);  // [2048][4096] = k_cross|v_cross

  dim3 tb32(32, 8);
  cast2_f32_bf16<<<8192, 256, 0, stream>>>(hidden, enc, hid_b, enc_b, 1048576);
  transpose_all<<<24576, tb32, 0, stream>>>(q_w, k_w, v_w, o_w, wqkvt, owt);
  gemm_proj<<<dim3(96, 16), 256, 0, stream>>>(hid_b, enc_b, wqkvt, cself, ccross);
  norm_all<<<16384, 256, 0, stream>>>(cself, ccross, q_s, k_s, pos, qb, kbuf);
  transpose_v2<<<dim3(8, 32, 32), tb32, 0, stream>>>(cself + 6144, ccross + 2048, vtb);
  attn_kernel<<<dim3(16, 16), 512, 0, stream>>>(qb, kbuf, vtb, attn_b);
  gemm_osplit<<<dim3(16, 16, 4), 256, 0, stream>>>(attn_b, owt, out, p1, p2, p3);
  add_inplace4<<<4096, 256, 0, stream>>>(out, p1, p2, p3, 1048576);
}